// Round 10
// baseline (137.067 us; speedup 1.0000x reference)
//
#include <hip/hip_runtime.h>

// Problem constants
#define HWC (512 * 512)           // H*W = 2^18
#define BATCH 4
#define NPIX (BATCH * HWC)        // 1,048,576 pixels

// -------------------------------------------------------------------------
// R9 = R8 + occupancy (4 blocks/CU) + split counted waits (LU overlaps R).
// R8 analysis: 8.3 B/cy/CU delivered = 81% of m13 copy ceiling ->
// delivery-bound; raise resident waves 12 -> 16 per CU for more outstanding
// requests. Split wait: vmcnt(18) retires x/m+D (queue order) -> LU runs
// while R loads finish -> vmcnt(9) retires R (S^T stores may remain).
// -------------------------------------------------------------------------

typedef float f4 __attribute__((ext_vector_type(4)));

#define GLOAD(dst, addr, off) \
    asm volatile("global_load_dwordx4 %0, %1, off offset:" #off \
                 : "=v"(dst) : "v"(addr))

// LU solve, one RHS: in w0..w5, out o0..o5 (uses lij, dij(U), rdk from scope)
#define SOLVE6(w0,w1,w2,w3,w4,w5, o0,o1,o2,o3,o4,o5)                      \
  {                                                                       \
    float t0 = (w0);                                                      \
    float t1 = (w1) - l10*t0;                                             \
    float t2 = (w2) - l20*t0 - l21*t1;                                    \
    float t3 = (w3) - l30*t0 - l31*t1 - l32*t2;                           \
    float t4 = (w4) - l40*t0 - l41*t1 - l42*t2 - l43*t3;                  \
    float t5 = (w5) - l50*t0 - l51*t1 - l52*t2 - l53*t3 - l54*t4;         \
    o5 = t5*rd5;                                                          \
    o4 = (t4 - d45*o5)*rd4;                                               \
    o3 = (t3 - d34*o4 - d35*o5)*rd3;                                      \
    o2 = (t2 - d23*o3 - d24*o4 - d25*o5)*rd2;                             \
    o1 = (t1 - d12*o2 - d13*o3 - d14*o4 - d15*o5)*rd1;                    \
    o0 = (t0 - d01*o1 - d02*o2 - d03*o3 - d04*o4 - d05*o5)*rd0;           \
  }

// s1[i][c] = sum_j r[i][j] * X[j][c]
#define S1(i,c) (r##i##0*X0_##c + r##i##1*X1_##c + r##i##2*X2_##c +       \
                 r##i##3*X3_##c + r##i##4*X4_##c + r##i##5*X5_##c)

#define LROW 260   // LDS row stride in floats (36 rows): write free, read 2-way

__global__ __launch_bounds__(256, 4) void gpenc_fused(
    const float* __restrict__ x,   // (B,3,HW)
    const float* __restrict__ m,   // (B,6,HW)
    const float* __restrict__ S,   // (B,HW,36)
    const float* __restrict__ R,   // (B,HW,36)
    const float* __restrict__ Dm,  // (B,HW,36)
    float* __restrict__ xout,      // (B,3,HW)
    float* __restrict__ yout,      // (B,3,HW)
    float* __restrict__ mout,      // (B,6,HW)
    float* __restrict__ Sout)      // (B,36,HW)
{
    __shared__ float lds[36 * LROW];          // 37.4 KB -> 4 blocks/CU

    const int t = threadIdx.x;
    const int g = blockIdx.x * 256 + t;
    const int b = g >> 18;                     // blockIdx.x >> 10
    const int p = g & (HWC - 1);
    const int pixbase = (blockIdx.x & 1023) * 256;

    // ---- 1. S loads (C-code; compiler tracks & waits these) ----
    const f4* S4 = reinterpret_cast<const f4*>(S + (size_t)g * 36);
    f4 s0 = S4[0], s1 = S4[1], s2 = S4[2], s3 = S4[3], s4 = S4[4],
       s5 = S4[5], s6 = S4[6], s7 = S4[7], s8 = S4[8];

    // ---- 2. x/m loads (early issue; consumed last) ----
    const size_t xb = (size_t)b * 3 * HWC + p;
    const size_t mb = (size_t)b * 6 * HWC + p;
    float xv0 = x[xb], xv1 = x[xb + (size_t)HWC], xv2 = x[xb + 2*(size_t)HWC];
    float mv0 = m[mb],                 mv1 = m[mb + (size_t)HWC],   mv2 = m[mb + 2*(size_t)HWC];
    float mv3 = m[mb + 3*(size_t)HWC], mv4 = m[mb + 4*(size_t)HWC], mv5 = m[mb + 5*(size_t)HWC];

    // ---- 3. S -> LDS, transposed layout lds[plane][pixel] ----
    lds[ 0*LROW + t] = s0.x; lds[ 1*LROW + t] = s0.y; lds[ 2*LROW + t] = s0.z; lds[ 3*LROW + t] = s0.w;
    lds[ 4*LROW + t] = s1.x; lds[ 5*LROW + t] = s1.y; lds[ 6*LROW + t] = s1.z; lds[ 7*LROW + t] = s1.w;
    lds[ 8*LROW + t] = s2.x; lds[ 9*LROW + t] = s2.y; lds[10*LROW + t] = s2.z; lds[11*LROW + t] = s2.w;
    lds[12*LROW + t] = s3.x; lds[13*LROW + t] = s3.y; lds[14*LROW + t] = s3.z; lds[15*LROW + t] = s3.w;
    lds[16*LROW + t] = s4.x; lds[17*LROW + t] = s4.y; lds[18*LROW + t] = s4.z; lds[19*LROW + t] = s4.w;
    lds[20*LROW + t] = s5.x; lds[21*LROW + t] = s5.y; lds[22*LROW + t] = s5.z; lds[23*LROW + t] = s5.w;
    lds[24*LROW + t] = s6.x; lds[25*LROW + t] = s6.y; lds[26*LROW + t] = s6.z; lds[27*LROW + t] = s6.w;
    lds[28*LROW + t] = s7.x; lds[29*LROW + t] = s7.y; lds[30*LROW + t] = s7.z; lds[31*LROW + t] = s7.w;
    lds[32*LROW + t] = s8.x; lds[33*LROW + t] = s8.y; lds[34*LROW + t] = s8.z; lds[35*LROW + t] = s8.w;

    // ---- 4. D then R asm loads (D oldest -> retires first) ----
    const float* dp = Dm + (size_t)g * 36;
    const float* rp = R  + (size_t)g * 36;
    f4 q0,q1,q2,q3,q4,q5,q6,q7,q8;
    f4 p0,p1,p2,p3,p4,p5,p6,p7,p8;
    GLOAD(q0, dp, 0);   GLOAD(q1, dp, 16);  GLOAD(q2, dp, 32);
    GLOAD(q3, dp, 48);  GLOAD(q4, dp, 64);  GLOAD(q5, dp, 80);
    GLOAD(q6, dp, 96);  GLOAD(q7, dp, 112); GLOAD(q8, dp, 128);
    GLOAD(p0, rp, 0);   GLOAD(p1, rp, 16);  GLOAD(p2, rp, 32);
    GLOAD(p3, rp, 48);  GLOAD(p4, rp, 64);  GLOAD(p5, rp, 80);
    GLOAD(p6, rp, 96);  GLOAD(p7, rp, 112); GLOAD(p8, rp, 128);

    // ---- 5. barrier, per-plane readback + float4 S^T stores ----
    __syncthreads();
    {
        const int w = t >> 6, l = t & 63;
        const f4* lds4 = reinterpret_cast<const f4*>(lds);   // row stride 65 f4
        float* so = Sout + (size_t)b * 36 * HWC + pixbase + 4 * l;
#pragma unroll
        for (int s = 0; s < 9; ++s) {
            const int j = s * 4 + w;                          // plane id
            f4 v = lds4[j * (LROW / 4) + l];
            *reinterpret_cast<f4*>(so + (size_t)j * HWC) = v;
        }
    }

    // ---- 6a. wait until only R+stores can remain -> D (and x/m) retired ----
    asm volatile("s_waitcnt vmcnt(18)" ::: "memory");
    __builtin_amdgcn_sched_barrier(0);   // rule #18

    // ---- unpack D ----
    float d00=q0.x, d01=q0.y, d02=q0.z, d03=q0.w;
    float d04=q1.x, d05=q1.y, d10=q1.z, d11=q1.w;
    float d12=q2.x, d13=q2.y, d14=q2.z, d15=q2.w;
    float d20=q3.x, d21=q3.y, d22=q3.z, d23=q3.w;
    float d24=q4.x, d25=q4.y, d30=q4.z, d31=q4.w;
    float d32=q5.x, d33=q5.y, d34=q5.z, d35=q5.w;
    float d40=q6.x, d41=q6.y, d42=q6.z, d43=q6.w;
    float d44=q7.x, d45=q7.y, d50=q7.z, d51=q7.w;
    float d52=q8.x, d53=q8.y, d54=q8.z, d55=q8.w;

    // ---- LU of D (overlaps the in-flight R loads) ----
    float rd0 = 1.0f/d00;
    float l10 = d10*rd0;
    d11 -= l10*d01; d12 -= l10*d02; d13 -= l10*d03; d14 -= l10*d04; d15 -= l10*d05;
    float l20 = d20*rd0;
    d21 -= l20*d01; d22 -= l20*d02; d23 -= l20*d03; d24 -= l20*d04; d25 -= l20*d05;
    float l30 = d30*rd0;
    d31 -= l30*d01; d32 -= l30*d02; d33 -= l30*d03; d34 -= l30*d04; d35 -= l30*d05;
    float l40 = d40*rd0;
    d41 -= l40*d01; d42 -= l40*d02; d43 -= l40*d03; d44 -= l40*d04; d45 -= l40*d05;
    float l50 = d50*rd0;
    d51 -= l50*d01; d52 -= l50*d02; d53 -= l50*d03; d54 -= l50*d04; d55 -= l50*d05;

    float rd1 = 1.0f/d11;
    float l21 = d21*rd1;
    d22 -= l21*d12; d23 -= l21*d13; d24 -= l21*d14; d25 -= l21*d15;
    float l31 = d31*rd1;
    d32 -= l31*d12; d33 -= l31*d13; d34 -= l31*d14; d35 -= l31*d15;
    float l41 = d41*rd1;
    d42 -= l41*d12; d43 -= l41*d13; d44 -= l41*d14; d45 -= l41*d15;
    float l51 = d51*rd1;
    d52 -= l51*d12; d53 -= l51*d13; d54 -= l51*d14; d55 -= l51*d15;

    float rd2 = 1.0f/d22;
    float l32 = d32*rd2;
    d33 -= l32*d23; d34 -= l32*d24; d35 -= l32*d25;
    float l42 = d42*rd2;
    d43 -= l42*d23; d44 -= l42*d24; d45 -= l42*d25;
    float l52 = d52*rd2;
    d53 -= l52*d23; d54 -= l52*d24; d55 -= l52*d25;

    float rd3 = 1.0f/d33;
    float l43 = d43*rd3;
    d44 -= l43*d34; d45 -= l43*d35;
    float l53 = d53*rd3;
    d54 -= l53*d34; d55 -= l53*d35;

    float rd4 = 1.0f/d44;
    float l54 = d54*rd4;
    d55 -= l54*d45;
    float rd5 = 1.0f/d55;

    // ---- 6b. wait for R (stores may remain outstanding) ----
    asm volatile("s_waitcnt vmcnt(9)" ::: "memory");
    __builtin_amdgcn_sched_barrier(0);   // rule #18

    float r00=p0.x, r01=p0.y, r02=p0.z, r03=p0.w;
    float r04=p1.x, r05=p1.y, r10=p1.z, r11=p1.w;
    float r12=p2.x, r13=p2.y, r14=p2.z, r15=p2.w;
    float r20=p3.x, r21=p3.y, r22=p3.z, r23=p3.w;
    float r24=p4.x, r25=p4.y, r30=p4.z, r31=p4.w;
    float r32=p5.x, r33=p5.y, r34=p5.z, r35=p5.w;
    float r40=p6.x, r41=p6.y, r42=p6.z, r43=p6.w;
    float r44=p7.x, r45=p7.y, r50=p7.z, r51=p7.w;
    float r52=p8.x, r53=p8.y, r54=p8.z, r55=p8.w;

    // ---- X = D^{-1} * R[0:3,:]^T ----
    float X0_0,X1_0,X2_0,X3_0,X4_0,X5_0;
    float X0_1,X1_1,X2_1,X3_1,X4_1,X5_1;
    float X0_2,X1_2,X2_2,X3_2,X4_2,X5_2;
    SOLVE6(r00,r01,r02,r03,r04,r05, X0_0,X1_0,X2_0,X3_0,X4_0,X5_0);
    SOLVE6(r10,r11,r12,r13,r14,r15, X0_1,X1_1,X2_1,X3_1,X4_1,X5_1);
    SOLVE6(r20,r21,r22,r23,r24,r25, X0_2,X1_2,X2_2,X3_2,X4_2,X5_2);

    // ---- S1c = R * X : Sxx rows 0..2 (a**), Syx rows 3..5 (b**) ----
    float a00=S1(0,0), a01=S1(0,1), a02=S1(0,2);
    float a10=S1(1,0), a11=S1(1,1), a12=S1(1,2);
    float a20=S1(2,0), a21=S1(2,1), a22=S1(2,2);
    float b00=S1(3,0), b01=S1(3,1), b02=S1(3,2);
    float b10=S1(4,0), b11=S1(4,1), b12=S1(4,2);
    float b20=S1(5,0), b21=S1(5,1), b22=S1(5,2);

    // ---- inv(Sxx) via adjugate ----
    float c00 =  (a11*a22 - a12*a21);
    float c01 = -(a10*a22 - a12*a20);
    float c02 =  (a10*a21 - a11*a20);
    float det = a00*c00 + a01*c01 + a02*c02;
    float rdet = 1.0f / det;
    float i00 = c00*rdet;
    float i01 = -(a01*a22 - a02*a21)*rdet;
    float i02 =  (a01*a12 - a02*a11)*rdet;
    float i10 = c01*rdet;
    float i11 =  (a00*a22 - a02*a20)*rdet;
    float i12 = -(a00*a12 - a02*a10)*rdet;
    float i20 = c02*rdet;
    float i21 = -(a00*a21 - a01*a20)*rdet;
    float i22 =  (a00*a11 - a01*a10)*rdet;

    // ---- Q = Syx * inv(Sxx) ----
    float Q00 = b00*i00 + b01*i10 + b02*i20;
    float Q01 = b00*i01 + b01*i11 + b02*i21;
    float Q02 = b00*i02 + b01*i12 + b02*i22;
    float Q10 = b10*i00 + b11*i10 + b12*i20;
    float Q11 = b10*i01 + b11*i11 + b12*i21;
    float Q12 = b10*i02 + b11*i12 + b12*i22;
    float Q20 = b20*i00 + b21*i10 + b22*i20;
    float Q21 = b20*i01 + b21*i11 + b22*i21;
    float Q22 = b20*i02 + b21*i12 + b22*i22;

    // ---- z = [dx, Q dx] ----
    float z0 = xv0 - mv0, z1v = xv1 - mv1, z2v = xv2 - mv2;
    float z3 = Q00*z0 + Q01*z1v + Q02*z2v;
    float z4 = Q10*z0 + Q11*z1v + Q12*z2v;
    float z5 = Q20*z0 + Q21*z1v + Q22*z2v;

    // ---- w = R z, rows 0..2 negated ----
    float w0 = -(r00*z0 + r01*z1v + r02*z2v + r03*z3 + r04*z4 + r05*z5);
    float w1 = -(r10*z0 + r11*z1v + r12*z2v + r13*z3 + r14*z4 + r15*z5);
    float w2 = -(r20*z0 + r21*z1v + r22*z2v + r23*z3 + r24*z4 + r25*z5);
    float w3 =  (r30*z0 + r31*z1v + r32*z2v + r33*z3 + r34*z4 + r35*z5);
    float w4 =  (r40*z0 + r41*z1v + r42*z2v + r43*z3 + r44*z4 + r45*z5);
    float w5 =  (r50*z0 + r51*z1v + r52*z2v + r53*z3 + r54*z4 + r55*z5);

    // ---- z2 = R^T w + m ----
    float o0 = w0*r00 + w1*r10 + w2*r20 + w3*r30 + w4*r40 + w5*r50 + mv0;
    float o1 = w0*r01 + w1*r11 + w2*r21 + w3*r31 + w4*r41 + w5*r51 + mv1;
    float o2 = w0*r02 + w1*r12 + w2*r22 + w3*r32 + w4*r42 + w5*r52 + mv2;
    float o3 = w0*r03 + w1*r13 + w2*r23 + w3*r33 + w4*r43 + w5*r53 + mv3;
    float o4 = w0*r04 + w1*r14 + w2*r24 + w3*r34 + w4*r44 + w5*r54 + mv4;
    float o5 = w0*r05 + w1*r15 + w2*r25 + w3*r35 + w4*r45 + w5*r55 + mv5;

    // ---- writes (coalesced plane-strided) ----
    xout[xb] = o0; xout[xb + (size_t)HWC] = o1; xout[xb + 2*(size_t)HWC] = o2;
    yout[xb] = o3; yout[xb + (size_t)HWC] = o4; yout[xb + 2*(size_t)HWC] = o5;
    mout[mb]                    = mv0;
    mout[mb + (size_t)HWC]      = mv1;
    mout[mb + 2*(size_t)HWC]    = mv2;
    mout[mb + 3*(size_t)HWC]    = mv3;
    mout[mb + 4*(size_t)HWC]    = mv4;
    mout[mb + 5*(size_t)HWC]    = mv5;
}

extern "C" void kernel_launch(void* const* d_in, const int* in_sizes, int n_in,
                              void* d_out, int out_size, void* d_ws, size_t ws_size,
                              hipStream_t stream) {
    // setup_inputs order: x, y(unused), m, S, R, D
    const float* x  = (const float*)d_in[0];
    const float* m  = (const float*)d_in[2];
    const float* S  = (const float*)d_in[3];
    const float* R  = (const float*)d_in[4];
    const float* D  = (const float*)d_in[5];

    float* out = (float*)d_out;
    const size_t N3 = (size_t)BATCH * 3 * HWC;   // 3,145,728
    const size_t N6 = (size_t)BATCH * 6 * HWC;   // 6,291,456
    float* xout = out;
    float* yout = out + N3;
    float* mout = out + 2 * N3;
    float* Sout = out + 2 * N3 + N6;

    gpenc_fused<<<NPIX / 256, 256, 0, stream>>>(x, m, S, R, D,
                                                xout, yout, mout, Sout);
}

// Round 12
// 136.141 us; speedup vs baseline: 1.0068x; 1.0068x over previous
//
#include <hip/hip_runtime.h>

// Problem constants
#define HWC (512 * 512)           // H*W = 2^18
#define BATCH 4
#define NPIX (BATCH * HWC)        // 1,048,576 pixels

// -------------------------------------------------------------------------
// R11 = R10 (two-pass S^T staging, 20.8 KB LDS) with __launch_bounds__(256,4).
// R10 post-mortem: (256,5) capped VGPRs at ~102 < ~113 live -> backend had
// to spill inline-asm load outputs whose values were still in flight (the
// compiler can't see the VMEM op inside asm volatile) -> abort. 128-reg cap
// holds the live set without spills; occupancy target 4 blocks/CU (50%).
// -------------------------------------------------------------------------

typedef float f4 __attribute__((ext_vector_type(4)));

#define GLOAD(dst, addr, off) \
    asm volatile("global_load_dwordx4 %0, %1, off offset:" #off \
                 : "=v"(dst) : "v"(addr))

// LU solve, one RHS: in w0..w5, out o0..o5 (uses lij, dij(U), rdk from scope)
#define SOLVE6(w0,w1,w2,w3,w4,w5, o0,o1,o2,o3,o4,o5)                      \
  {                                                                       \
    float t0 = (w0);                                                      \
    float t1 = (w1) - l10*t0;                                             \
    float t2 = (w2) - l20*t0 - l21*t1;                                    \
    float t3 = (w3) - l30*t0 - l31*t1 - l32*t2;                           \
    float t4 = (w4) - l40*t0 - l41*t1 - l42*t2 - l43*t3;                  \
    float t5 = (w5) - l50*t0 - l51*t1 - l52*t2 - l53*t3 - l54*t4;         \
    o5 = t5*rd5;                                                          \
    o4 = (t4 - d45*o5)*rd4;                                               \
    o3 = (t3 - d34*o4 - d35*o5)*rd3;                                      \
    o2 = (t2 - d23*o3 - d24*o4 - d25*o5)*rd2;                             \
    o1 = (t1 - d12*o2 - d13*o3 - d14*o4 - d15*o5)*rd1;                    \
    o0 = (t0 - d01*o1 - d02*o2 - d03*o3 - d04*o4 - d05*o5)*rd0;           \
  }

// s1[i][c] = sum_j r[i][j] * X[j][c]
#define S1(i,c) (r##i##0*X0_##c + r##i##1*X1_##c + r##i##2*X2_##c +       \
                 r##i##3*X3_##c + r##i##4*X4_##c + r##i##5*X5_##c)

#define LROW 260   // LDS row stride in floats: write 2-lanes/bank (free),
                   // f4 read conflict-free (lanes 0..7 cover all 32 banks)

__global__ __launch_bounds__(256, 4) void gpenc_fused(
    const float* __restrict__ x,   // (B,3,HW)
    const float* __restrict__ m,   // (B,6,HW)
    const float* __restrict__ S,   // (B,HW,36)
    const float* __restrict__ R,   // (B,HW,36)
    const float* __restrict__ Dm,  // (B,HW,36)
    float* __restrict__ xout,      // (B,3,HW)
    float* __restrict__ yout,      // (B,3,HW)
    float* __restrict__ mout,      // (B,6,HW)
    float* __restrict__ Sout)      // (B,36,HW)
{
    __shared__ float lds[20 * LROW];          // 20.8 KB

    const int t = threadIdx.x;
    const int g = blockIdx.x * 256 + t;
    const int b = g >> 18;                     // blockIdx.x >> 10
    const int p = g & (HWC - 1);
    const int pixbase = (blockIdx.x & 1023) * 256;

    // ---- 1. S loads (C-code; compiler tracks & waits these) ----
    const f4* S4 = reinterpret_cast<const f4*>(S + (size_t)g * 36);
    f4 s0 = S4[0], s1 = S4[1], s2 = S4[2], s3 = S4[3], s4 = S4[4],
       s5 = S4[5], s6 = S4[6], s7 = S4[7], s8 = S4[8];

    // ---- 2. x/m loads; sched_barrier pins their issue HERE (older than
    //         the D/R asm loads -> the later vmcnt(9) count is sound) ----
    const size_t xb = (size_t)b * 3 * HWC + p;
    const size_t mb = (size_t)b * 6 * HWC + p;
    float xv0 = x[xb], xv1 = x[xb + (size_t)HWC], xv2 = x[xb + 2*(size_t)HWC];
    float mv0 = m[mb],                 mv1 = m[mb + (size_t)HWC],   mv2 = m[mb + 2*(size_t)HWC];
    float mv3 = m[mb + 3*(size_t)HWC], mv4 = m[mb + 4*(size_t)HWC], mv5 = m[mb + 5*(size_t)HWC];
    __builtin_amdgcn_sched_barrier(0);

    // ---- 3. S -> LDS half 1: planes 0..15 (s0..s3 die here) ----
    lds[ 0*LROW + t] = s0.x; lds[ 1*LROW + t] = s0.y; lds[ 2*LROW + t] = s0.z; lds[ 3*LROW + t] = s0.w;
    lds[ 4*LROW + t] = s1.x; lds[ 5*LROW + t] = s1.y; lds[ 6*LROW + t] = s1.z; lds[ 7*LROW + t] = s1.w;
    lds[ 8*LROW + t] = s2.x; lds[ 9*LROW + t] = s2.y; lds[10*LROW + t] = s2.z; lds[11*LROW + t] = s2.w;
    lds[12*LROW + t] = s3.x; lds[13*LROW + t] = s3.y; lds[14*LROW + t] = s3.z; lds[15*LROW + t] = s3.w;

    // ---- 4. D then R asm loads (youngest VMEM before the stores) ----
    const float* dp = Dm + (size_t)g * 36;
    const float* rp = R  + (size_t)g * 36;
    f4 q0,q1,q2,q3,q4,q5,q6,q7,q8;
    f4 p0,p1,p2,p3,p4,p5,p6,p7,p8;
    GLOAD(q0, dp, 0);   GLOAD(q1, dp, 16);  GLOAD(q2, dp, 32);
    GLOAD(q3, dp, 48);  GLOAD(q4, dp, 64);  GLOAD(q5, dp, 80);
    GLOAD(q6, dp, 96);  GLOAD(q7, dp, 112); GLOAD(q8, dp, 128);
    GLOAD(p0, rp, 0);   GLOAD(p1, rp, 16);  GLOAD(p2, rp, 32);
    GLOAD(p3, rp, 48);  GLOAD(p4, rp, 64);  GLOAD(p5, rp, 80);
    GLOAD(p6, rp, 96);  GLOAD(p7, rp, 112); GLOAD(p8, rp, 128);

    const int w = t >> 6, l = t & 63;
    const f4* lds4 = reinterpret_cast<const f4*>(lds);   // row stride 65 f4
    float* so = Sout + (size_t)b * 36 * HWC + pixbase + 4 * l;

    // ---- 5. half-1 readback + 4 float4 S^T stores ----
    __syncthreads();
#pragma unroll
    for (int s = 0; s < 4; ++s) {
        const int j = s * 4 + w;                          // plane 0..15
        f4 v = lds4[j * (LROW / 4) + l];
        *reinterpret_cast<f4*>(so + (size_t)j * HWC) = v;
    }
    __syncthreads();   // half-1 reads done before half-2 overwrites

    // ---- 6. S -> LDS half 2: planes 16..35 in rows 0..19 ----
    lds[ 0*LROW + t] = s4.x; lds[ 1*LROW + t] = s4.y; lds[ 2*LROW + t] = s4.z; lds[ 3*LROW + t] = s4.w;
    lds[ 4*LROW + t] = s5.x; lds[ 5*LROW + t] = s5.y; lds[ 6*LROW + t] = s5.z; lds[ 7*LROW + t] = s5.w;
    lds[ 8*LROW + t] = s6.x; lds[ 9*LROW + t] = s6.y; lds[10*LROW + t] = s6.z; lds[11*LROW + t] = s6.w;
    lds[12*LROW + t] = s7.x; lds[13*LROW + t] = s7.y; lds[14*LROW + t] = s7.z; lds[15*LROW + t] = s7.w;
    lds[16*LROW + t] = s8.x; lds[17*LROW + t] = s8.y; lds[18*LROW + t] = s8.z; lds[19*LROW + t] = s8.w;
    __syncthreads();

    // ---- 7. half-2 readback + 5 float4 S^T stores ----
#pragma unroll
    for (int s = 0; s < 5; ++s) {
        const int jr = s * 4 + w;                         // row 0..19
        f4 v = lds4[jr * (LROW / 4) + l];
        *reinterpret_cast<f4*>(so + (size_t)(16 + jr) * HWC) = v;
    }

    // ---- 8. one counted wait: only the 9 S^T stores are younger than the
    //         last R load -> outstanding<=9 means all D/R (and x/m) retired ----
    asm volatile("s_waitcnt vmcnt(9)" ::: "memory");
    __builtin_amdgcn_sched_barrier(0);   // rule #18

    // ---- unpack D ----
    float d00=q0.x, d01=q0.y, d02=q0.z, d03=q0.w;
    float d04=q1.x, d05=q1.y, d10=q1.z, d11=q1.w;
    float d12=q2.x, d13=q2.y, d14=q2.z, d15=q2.w;
    float d20=q3.x, d21=q3.y, d22=q3.z, d23=q3.w;
    float d24=q4.x, d25=q4.y, d30=q4.z, d31=q4.w;
    float d32=q5.x, d33=q5.y, d34=q5.z, d35=q5.w;
    float d40=q6.x, d41=q6.y, d42=q6.z, d43=q6.w;
    float d44=q7.x, d45=q7.y, d50=q7.z, d51=q7.w;
    float d52=q8.x, d53=q8.y, d54=q8.z, d55=q8.w;

    // ---- LU of D in place, fully unrolled (Doolittle, no pivot; D ~ 2I) ----
    float rd0 = 1.0f/d00;
    float l10 = d10*rd0;
    d11 -= l10*d01; d12 -= l10*d02; d13 -= l10*d03; d14 -= l10*d04; d15 -= l10*d05;
    float l20 = d20*rd0;
    d21 -= l20*d01; d22 -= l20*d02; d23 -= l20*d03; d24 -= l20*d04; d25 -= l20*d05;
    float l30 = d30*rd0;
    d31 -= l30*d01; d32 -= l30*d02; d33 -= l30*d03; d34 -= l30*d04; d35 -= l30*d05;
    float l40 = d40*rd0;
    d41 -= l40*d01; d42 -= l40*d02; d43 -= l40*d03; d44 -= l40*d04; d45 -= l40*d05;
    float l50 = d50*rd0;
    d51 -= l50*d01; d52 -= l50*d02; d53 -= l50*d03; d54 -= l50*d04; d55 -= l50*d05;

    float rd1 = 1.0f/d11;
    float l21 = d21*rd1;
    d22 -= l21*d12; d23 -= l21*d13; d24 -= l21*d14; d25 -= l21*d15;
    float l31 = d31*rd1;
    d32 -= l31*d12; d33 -= l31*d13; d34 -= l31*d14; d35 -= l31*d15;
    float l41 = d41*rd1;
    d42 -= l41*d12; d43 -= l41*d13; d44 -= l41*d14; d45 -= l41*d15;
    float l51 = d51*rd1;
    d52 -= l51*d12; d53 -= l51*d13; d54 -= l51*d14; d55 -= l51*d15;

    float rd2 = 1.0f/d22;
    float l32 = d32*rd2;
    d33 -= l32*d23; d34 -= l32*d24; d35 -= l32*d25;
    float l42 = d42*rd2;
    d43 -= l42*d23; d44 -= l42*d24; d45 -= l42*d25;
    float l52 = d52*rd2;
    d53 -= l52*d23; d54 -= l52*d24; d55 -= l52*d25;

    float rd3 = 1.0f/d33;
    float l43 = d43*rd3;
    d44 -= l43*d34; d45 -= l43*d35;
    float l53 = d53*rd3;
    d54 -= l53*d34; d55 -= l53*d35;

    float rd4 = 1.0f/d44;
    float l54 = d54*rd4;
    d55 -= l54*d45;
    float rd5 = 1.0f/d55;

    // ---- unpack R ----
    float r00=p0.x, r01=p0.y, r02=p0.z, r03=p0.w;
    float r04=p1.x, r05=p1.y, r10=p1.z, r11=p1.w;
    float r12=p2.x, r13=p2.y, r14=p2.z, r15=p2.w;
    float r20=p3.x, r21=p3.y, r22=p3.z, r23=p3.w;
    float r24=p4.x, r25=p4.y, r30=p4.z, r31=p4.w;
    float r32=p5.x, r33=p5.y, r34=p5.z, r35=p5.w;
    float r40=p6.x, r41=p6.y, r42=p6.z, r43=p6.w;
    float r44=p7.x, r45=p7.y, r50=p7.z, r51=p7.w;
    float r52=p8.x, r53=p8.y, r54=p8.z, r55=p8.w;

    // ---- X = D^{-1} * R[0:3,:]^T ----
    float X0_0,X1_0,X2_0,X3_0,X4_0,X5_0;
    float X0_1,X1_1,X2_1,X3_1,X4_1,X5_1;
    float X0_2,X1_2,X2_2,X3_2,X4_2,X5_2;
    SOLVE6(r00,r01,r02,r03,r04,r05, X0_0,X1_0,X2_0,X3_0,X4_0,X5_0);
    SOLVE6(r10,r11,r12,r13,r14,r15, X0_1,X1_1,X2_1,X3_1,X4_1,X5_1);
    SOLVE6(r20,r21,r22,r23,r24,r25, X0_2,X1_2,X2_2,X3_2,X4_2,X5_2);

    // ---- S1c = R * X : Sxx rows 0..2 (a**), Syx rows 3..5 (b**) ----
    float a00=S1(0,0), a01=S1(0,1), a02=S1(0,2);
    float a10=S1(1,0), a11=S1(1,1), a12=S1(1,2);
    float a20=S1(2,0), a21=S1(2,1), a22=S1(2,2);
    float b00=S1(3,0), b01=S1(3,1), b02=S1(3,2);
    float b10=S1(4,0), b11=S1(4,1), b12=S1(4,2);
    float b20=S1(5,0), b21=S1(5,1), b22=S1(5,2);

    // ---- inv(Sxx) via adjugate ----
    float c00 =  (a11*a22 - a12*a21);
    float c01 = -(a10*a22 - a12*a20);
    float c02 =  (a10*a21 - a11*a20);
    float det = a00*c00 + a01*c01 + a02*c02;
    float rdet = 1.0f / det;
    float i00 = c00*rdet;
    float i01 = -(a01*a22 - a02*a21)*rdet;
    float i02 =  (a01*a12 - a02*a11)*rdet;
    float i10 = c01*rdet;
    float i11 =  (a00*a22 - a02*a20)*rdet;
    float i12 = -(a00*a12 - a02*a10)*rdet;
    float i20 = c02*rdet;
    float i21 = -(a00*a21 - a01*a20)*rdet;
    float i22 =  (a00*a11 - a01*a10)*rdet;

    // ---- Q = Syx * inv(Sxx) ----
    float Q00 = b00*i00 + b01*i10 + b02*i20;
    float Q01 = b00*i01 + b01*i11 + b02*i21;
    float Q02 = b00*i02 + b01*i12 + b02*i22;
    float Q10 = b10*i00 + b11*i10 + b12*i20;
    float Q11 = b10*i01 + b11*i11 + b12*i21;
    float Q12 = b10*i02 + b11*i12 + b12*i22;
    float Q20 = b20*i00 + b21*i10 + b22*i20;
    float Q21 = b20*i01 + b21*i11 + b22*i21;
    float Q22 = b20*i02 + b21*i12 + b22*i22;

    // ---- z = [dx, Q dx] ----
    float z0 = xv0 - mv0, z1v = xv1 - mv1, z2v = xv2 - mv2;
    float z3 = Q00*z0 + Q01*z1v + Q02*z2v;
    float z4 = Q10*z0 + Q11*z1v + Q12*z2v;
    float z5 = Q20*z0 + Q21*z1v + Q22*z2v;

    // ---- w = R z, rows 0..2 negated ----
    float w0 = -(r00*z0 + r01*z1v + r02*z2v + r03*z3 + r04*z4 + r05*z5);
    float w1 = -(r10*z0 + r11*z1v + r12*z2v + r13*z3 + r14*z4 + r15*z5);
    float w2 = -(r20*z0 + r21*z1v + r22*z2v + r23*z3 + r24*z4 + r25*z5);
    float w3 =  (r30*z0 + r31*z1v + r32*z2v + r33*z3 + r34*z4 + r35*z5);
    float w4 =  (r40*z0 + r41*z1v + r42*z2v + r43*z3 + r44*z4 + r45*z5);
    float w5 =  (r50*z0 + r51*z1v + r52*z2v + r53*z3 + r54*z4 + r55*z5);

    // ---- z2 = R^T w + m ----
    float o0 = w0*r00 + w1*r10 + w2*r20 + w3*r30 + w4*r40 + w5*r50 + mv0;
    float o1 = w0*r01 + w1*r11 + w2*r21 + w3*r31 + w4*r41 + w5*r51 + mv1;
    float o2 = w0*r02 + w1*r12 + w2*r22 + w3*r32 + w4*r42 + w5*r52 + mv2;
    float o3 = w0*r03 + w1*r13 + w2*r23 + w3*r33 + w4*r43 + w5*r53 + mv3;
    float o4 = w0*r04 + w1*r14 + w2*r24 + w3*r34 + w4*r44 + w5*r54 + mv4;
    float o5 = w0*r05 + w1*r15 + w2*r25 + w3*r35 + w4*r45 + w5*r55 + mv5;

    // ---- writes (coalesced plane-strided) ----
    xout[xb] = o0; xout[xb + (size_t)HWC] = o1; xout[xb + 2*(size_t)HWC] = o2;
    yout[xb] = o3; yout[xb + (size_t)HWC] = o4; yout[xb + 2*(size_t)HWC] = o5;
    mout[mb]                    = mv0;
    mout[mb + (size_t)HWC]      = mv1;
    mout[mb + 2*(size_t)HWC]    = mv2;
    mout[mb + 3*(size_t)HWC]    = mv3;
    mout[mb + 4*(size_t)HWC]    = mv4;
    mout[mb + 5*(size_t)HWC]    = mv5;
}

extern "C" void kernel_launch(void* const* d_in, const int* in_sizes, int n_in,
                              void* d_out, int out_size, void* d_ws, size_t ws_size,
                              hipStream_t stream) {
    // setup_inputs order: x, y(unused), m, S, R, D
    const float* x  = (const float*)d_in[0];
    const float* m  = (const float*)d_in[2];
    const float* S  = (const float*)d_in[3];
    const float* R  = (const float*)d_in[4];
    const float* D  = (const float*)d_in[5];

    float* out = (float*)d_out;
    const size_t N3 = (size_t)BATCH * 3 * HWC;   // 3,145,728
    const size_t N6 = (size_t)BATCH * 6 * HWC;   // 6,291,456
    float* xout = out;
    float* yout = out + N3;
    float* mout = out + 2 * N3;
    float* Sout = out + 2 * N3 + N6;

    gpenc_fused<<<NPIX / 256, 256, 0, stream>>>(x, m, S, R, D,
                                                xout, yout, mout, Sout);
}